// Round 17
// baseline (32.127 us; speedup 1.0000x reference)
//
#include <hip/hip_runtime.h>
#include <hip/hip_bf16.h>

#define D_DIM   256
#define N_TOT   4096
#define N_ANCH  256
#define NGRP    32                    // anchor groups of 8 (128 rows)
#define NOFF    496                   // strict upper-triangle tiles (g<s)
#define NBLK    512                   // 496 off-diag + 16 dual-diagonal blocks
#define NPART   64                    // partNeg slots per row
#define K1  20.60992915555662f        // (1/0.07) * log2(e)
#define LN2 0.6931471805599453f
#define MAXNP    48                   // max anchors per label (19 labels, mean 13.5)

typedef __attribute__((ext_vector_type(8))) short bf16x8;
typedef __attribute__((ext_vector_type(4))) float f32x4;

#define MFMA(a, b, c) __builtin_amdgcn_mfma_f32_16x16x32_bf16((a), (b), (c), 0, 0, 0)

__device__ __forceinline__ bf16x8 cvt8(const float4 a, const float4 b) {
    union { uint32_t w[4]; bf16x8 v; } u;
    asm("v_cvt_pk_bf16_f32 %0, %1, %2" : "=v"(u.w[0]) : "v"(a.x), "v"(a.y));
    asm("v_cvt_pk_bf16_f32 %0, %1, %2" : "=v"(u.w[1]) : "v"(a.z), "v"(a.w));
    asm("v_cvt_pk_bf16_f32 %0, %1, %2" : "=v"(u.w[2]) : "v"(b.x), "v"(b.y));
    asm("v_cvt_pk_bf16_f32 %0, %1, %2" : "=v"(u.w[3]) : "v"(b.z), "v"(b.w));
    return u.v;
}

// ---------- kernel 1: symmetric 128x128-tile fused GEMM (r13 core, neg-only partials) ----------
// 512 blocks: 0..495 strict-upper tiles (XCD-swizzled), 496..511 two diagonal tiles each.
// Epilogue accumulates exp sums ONLY for different-label (negative) tiles, so
// partNeg slots sum directly to ns in passB (no sE correction pass needed).
__global__ void __launch_bounds__(256, 2) k_pass1(const float* __restrict__ feats,
                                                  const int* __restrict__ labels,
                                                  float* __restrict__ partNeg,
                                                  float* __restrict__ posBuf,
                                                  float* __restrict__ out) {
    __shared__ __align__(16) char lds[65536];   // A: [0,32K), B: [32K,64K)
    __shared__ float scrS[1024];                // 4 waves x 256: transpose scratch (separate!)
    __shared__ int labS[N_ANCH];
    __shared__ int cntS[32];
    __shared__ int metaRank[16], metaToff[16];

    if (blockIdx.x == 0 && threadIdx.x == 0) out[0] = 0.f;   // passB accumulates later

    const int tid = threadIdx.x;
    const int lane = tid & 63, wid = tid >> 6;
    const int lrow = lane & 15, khalf = lane >> 4;
    const int wr = wid >> 1, wc = wid & 1;      // wave sub-tile (wr*64, wc*64)

    // label table + histogram (persists across tiles)
    labS[tid] = labels[tid];
    if (tid < 32) cntS[tid] = 0;
    __syncthreads();
    atomicAdd(&cntS[labS[tid]], 1);
    // (first in-tile __syncthreads covers the histogram)

    // staging decode: linear bf16 LDS byte L -> fp32 source offset + swizzled LDS byte
    uint32_t LgF[8], Lw[8];
#pragma unroll
    for (int o = 0; o < 8; ++o) {
        uint32_t L = (uint32_t)(tid * 16 + o * 4096);
        LgF[o] = (L >> 8) * 1024 + ((L & 255) << 1);       // row*1024B + colelem*4B
        Lw[o]  = L ^ (((L >> 8) & 7u) << 4);               // swizzled LDS byte
    }
    const uint32_t swz = (uint32_t)((lrow & 7) << 4);

    auto gemm_tile = [&](int g, int s) {
        const bool diag = (g == s);
        const char* aSrcF = (const char*)(feats + (size_t)g * 128 * D_DIM);
        const char* bSrcF = (const char*)(feats + (size_t)s * 128 * D_DIM);
        const uint32_t bBase = diag ? 0u : 32768u;   // diagonal: B-frags read A region

        f32x4 acc[4][4];
#pragma unroll
        for (int m = 0; m < 4; ++m)
#pragma unroll
            for (int n = 0; n < 4; ++n)
                acc[m][n] = (f32x4){0.f, 0.f, 0.f, 0.f};

        auto compute = [&]() {
#pragma unroll
            for (int ks = 0; ks < 4; ++ks) {
                bf16x8 af[4], bfr[4];
#pragma unroll
                for (int m = 0; m < 4; ++m) {
                    uint32_t row = (uint32_t)(wr * 64 + m * 16 + lrow);
                    af[m] = *(const bf16x8*)(lds + ((row * 256 + ks * 64 + khalf * 16) ^ swz));
                }
#pragma unroll
                for (int n = 0; n < 4; ++n) {
                    uint32_t row = (uint32_t)(wc * 64 + n * 16 + lrow);
                    bfr[n] = *(const bf16x8*)(lds + bBase + ((row * 256 + ks * 64 + khalf * 16) ^ swz));
                }
#pragma unroll
                for (int m = 0; m < 4; ++m)
#pragma unroll
                    for (int n = 0; n < 4; ++n)
                        acc[m][n] = MFMA(af[m], bfr[n], acc[m][n]);
            }
        };

        // ---- stage chunk 0 (A, and B if off-diag) ----
        {
            float4 fa[8][2], fb[8][2];
#pragma unroll
            for (int o = 0; o < 8; ++o) {
                const char* pa = aSrcF + LgF[o];
                fa[o][0] = *(const float4*)pa;  fa[o][1] = *(const float4*)(pa + 16);
            }
            if (!diag) {
#pragma unroll
                for (int o = 0; o < 8; ++o) {
                    const char* pb = bSrcF + LgF[o];
                    fb[o][0] = *(const float4*)pb;  fb[o][1] = *(const float4*)(pb + 16);
                }
            }
#pragma unroll
            for (int o = 0; o < 8; ++o)
                *(bf16x8*)(lds + Lw[o]) = cvt8(fa[o][0], fa[o][1]);
            if (!diag) {
#pragma unroll
                for (int o = 0; o < 8; ++o)
                    *(bf16x8*)(lds + 32768 + Lw[o]) = cvt8(fb[o][0], fb[o][1]);
            }
        }
        __syncthreads();        // chunk 0 ready (also covers histogram / prev tile)

        // ---- prefetch A chunk 1 into registers (latency hides under meta + compute 0) ----
        float4 pfa[8][2];
#pragma unroll
        for (int o = 0; o < 8; ++o) {
            const char* pa = aSrcF + LgF[o] + 512;
            pfa[o][0] = *(const float4*)pa;  pfa[o][1] = *(const float4*)(pa + 16);
        }

        // per-tile metadata: 16 anchors x 16 workers
        {
            int aIdx = tid >> 4, q = tid & 15;
            int aAnchor = (aIdx < 8) ? (g * 8 + aIdx) : (s * 8 + aIdx - 8);
            int la = labS[aAnchor];
            int rk = 0, tf = 0;
            for (int b = q; b < aAnchor; b += 16) {
                int lb = labS[b];
                rk += (lb == la);
                tf += cntS[lb];
            }
#pragma unroll
            for (int msk = 1; msk < 16; msk <<= 1) {
                rk += __shfl_xor(rk, msk, 64);
                tf += __shfl_xor(tf, msk, 64);
            }
            if (q == 0) { metaRank[aIdx] = rk; metaToff[aIdx] = tf; }
        }

        compute();              // chunk 0
        __syncthreads();        // reads of chunk 0 done

        // ---- stage chunk 1: write prefetched A; load+write B ----
#pragma unroll
        for (int o = 0; o < 8; ++o)
            *(bf16x8*)(lds + Lw[o]) = cvt8(pfa[o][0], pfa[o][1]);
        if (!diag) {
            float4 fb[8][2];
#pragma unroll
            for (int o = 0; o < 8; ++o) {
                const char* pb = bSrcF + LgF[o] + 512;
                fb[o][0] = *(const float4*)pb;  fb[o][1] = *(const float4*)(pb + 16);
            }
#pragma unroll
            for (int o = 0; o < 8; ++o)
                *(bf16x8*)(lds + 32768 + Lw[o]) = cvt8(fb[o][0], fb[o][1]);
        }
        __syncthreads();        // chunk 1 ready (meta visible)
        compute();
        // no barrier: epilogue uses only scrS (separate region) + registers

        // ---- epilogue: NEG-only row/col exp sums + positive-tile stores ----
        const int raBase = g * 8 + wr * 4, caBase = s * 8 + wc * 4;
        int labR[4], offR[4], rankR[4], labC[4], rankC[4], offC[4];
#pragma unroll
        for (int m = 0; m < 4; ++m) {
            labR[m]  = labS[raBase + m];
            offR[m]  = metaToff[wr * 4 + m];
            rankR[m] = metaRank[wr * 4 + m];
        }
#pragma unroll
        for (int n = 0; n < 4; ++n) {
            labC[n]  = labS[caBase + n];
            rankC[n] = metaRank[8 + wc * 4 + n];
            offC[n]  = metaToff[8 + wc * 4 + n];
        }

        float aNeg[4][4];       // neg-only direct row sums [m][i]
        float colP[4];          // neg-only per-lane col partials [n]
#pragma unroll
        for (int m = 0; m < 4; ++m)
#pragma unroll
            for (int i = 0; i < 4; ++i) aNeg[m][i] = 0.f;
#pragma unroll
        for (int n = 0; n < 4; ++n) colP[n] = 0.f;

        float* scr = scrS + wid * 256;   // per-wave transpose scratch (dedicated LDS)

#pragma unroll
        for (int m = 0; m < 4; ++m) {
#pragma unroll
            for (int n = 0; n < 4; ++n) {
                f32x4 c = acc[m][n];
                if (labR[m] == labC[n]) {    // positive tile: store raw scores only
                    *(f32x4*)(posBuf + (size_t)(offR[m] + rankC[n]) * 256 + lane * 4) = c;
                    if (!diag) {
#pragma unroll
                        for (int i = 0; i < 4; ++i)
                            scr[(khalf * 4 + i) * 16 + lrow] = c[i];
                        __builtin_amdgcn_s_waitcnt(0);          // wave-local LDS RAW
                        f32x4 tr = *(f32x4*)(scr + lrow * 16 + khalf * 4);
                        *(f32x4*)(posBuf + (size_t)(offC[n] + rankR[m]) * 256 + lane * 4) = tr;
                    }
                } else {                     // negative tile: exp sums
                    float e[4];
#pragma unroll
                    for (int i = 0; i < 4; ++i) {
                        e[i] = exp2f(__builtin_fmaf(c[i], K1, -K1));
                        aNeg[m][i] += e[i];
                    }
                    if (!diag)
                        colP[n] += e[0] + e[1] + e[2] + e[3];
                }
            }
        }

#pragma unroll
        for (int msk = 1; msk < 16; msk <<= 1)
#pragma unroll
            for (int m = 0; m < 4; ++m)
#pragma unroll
                for (int i = 0; i < 4; ++i)
                    aNeg[m][i] += __shfl_xor(aNeg[m][i], msk, 64);

        if (lrow == 0) {
#pragma unroll
            for (int m = 0; m < 4; ++m)
#pragma unroll
                for (int i = 0; i < 4; ++i) {
                    int row = g * 128 + wr * 64 + m * 16 + khalf * 4 + i;
                    partNeg[row * NPART + s * 2 + wc] = aNeg[m][i];
                }
        }

        if (!diag) {
#pragma unroll
            for (int msk = 16; msk < 64; msk <<= 1)
#pragma unroll
                for (int n = 0; n < 4; ++n)
                    colP[n] += __shfl_xor(colP[n], msk, 64);
            if (lane < 16) {
#pragma unroll
                for (int n = 0; n < 4; ++n) {
                    int row = s * 128 + wc * 64 + n * 16 + lane;
                    partNeg[row * NPART + g * 2 + wr] = colP[n];
                }
            }
        }
        __syncthreads();        // compute reads done before any next-tile staging
    };

    if (blockIdx.x < NOFF) {
        // strict upper triangle (g<s), XCD-swizzled (496 = 8*62)
        int swzId = (blockIdx.x & 7) * 62 + (blockIdx.x >> 3);
        int rem = swzId, g = 0;
        while (rem >= NGRP - 1 - g) { rem -= NGRP - 1 - g; ++g; }
        gemm_tile(g, g + 1 + rem);
    } else {
        int j = blockIdx.x - NOFF;     // 0..15 -> two diagonal tiles each
        gemm_tile(2 * j, 2 * j);
        gemm_tile(2 * j + 1, 2 * j + 1);
    }
}

// ---------- kernel 2: single-loop positive pass + atomic final ----------
// ns comes directly from partNeg (neg-only sums) -> no sE pass, one np-loop.
__global__ void __launch_bounds__(256) k_passB(const float* __restrict__ posBuf,
                                               const int* __restrict__ labels,
                                               const float* __restrict__ partNeg,
                                               float* __restrict__ out) {
    int rt  = blockIdx.x;
    int tid = threadIdx.x;
    int l = tid >> 2, i = tid & 3;
    int r   = (l >> 4) * 4 + i;        // row within tile (fixed per thread)
    int col = l & 15;
    int row16 = tid >> 4;              // reduction role: row
    int q16   = tid & 15;              //   and 16-way slice

    __shared__ float shA[16][17];
    __shared__ float shB[16][17];
    __shared__ float nsSh[16];
    __shared__ int labS[N_ANCH];
    __shared__ int cntS[32];
    __shared__ int wRk[4], wTf[4];
    __shared__ int mNp, mOff, mRank;

    // in-block metadata for anchor rt
    labS[tid] = labels[tid];
    if (tid < 32) cntS[tid] = 0;
    __syncthreads();
    atomicAdd(&cntS[labS[tid]], 1);
    __syncthreads();
    {
        int la = labS[rt];
        int rk = 0, tf = 0;
        if (tid < rt) { int lb = labS[tid]; rk = (lb == la) ? 1 : 0; tf = cntS[lb]; }
#pragma unroll
        for (int msk = 1; msk < 64; msk <<= 1) {
            rk += __shfl_xor(rk, msk, 64);
            tf += __shfl_xor(tf, msk, 64);
        }
        if ((tid & 63) == 0) { wRk[tid >> 6] = rk; wTf[tid >> 6] = tf; }
        __syncthreads();
        if (tid == 0) {
            mNp   = cntS[la];
            mRank = wRk[0] + wRk[1] + wRk[2] + wRk[3];
            mOff  = wTf[0] + wTf[1] + wTf[2] + wTf[3];
        }
    }

    // parallel ns reduce: thread (row16,q16) sums one float4 of partNeg
    {
        const float* pa = partNeg + (size_t)(rt * 16 + row16) * NPART + q16 * 4;
        float4 v = *(const float4*)pa;
        float ns = v.x + v.y + v.z + v.w;
#pragma unroll
        for (int msk = 1; msk < 16; msk <<= 1)
            ns += __shfl_xor(ns, msk, 64);
        if (q16 == 0) nsSh[row16] = ns;
    }
    __syncthreads();           // nsSh + meta (mNp/mOff/mRank) visible

    int np = mNp, off = mOff, selfRank = mRank;
    float nsv = nsSh[r];

    // single loop: sP (positive logit sum) and sL (log-denominator sum)
    float sP = 0.f, sL = 0.f;
    const float* src = posBuf + (size_t)off * 256 + tid;
    for (int j = 0; j < np; ++j) {
        float c = src[j * 256];
        float l2 = __builtin_fmaf(c, K1, -K1);
        float e = exp2f(l2);
        float lg = __log2f(e + nsv);
        bool dg = (j == selfRank) & (col == r);
        sP += dg ? 0.f : l2;
        sL += dg ? 0.f : lg;
    }
    shA[r][col] = sP;
    shB[r][col] = sL;
    __syncthreads();

    // parallel reduce: per-row P and L -> contribution
    {
        float P = shA[row16][q16];
        float L = shB[row16][q16];
#pragma unroll
        for (int msk = 1; msk < 16; msk <<= 1) {
            P += __shfl_xor(P, msk, 64);
            L += __shfl_xor(L, msk, 64);
        }
        if (q16 == 0)
            nsSh[row16] = (P - L) / (float)(16 * np - 1);   // reuse nsSh as row contrib
    }
    __syncthreads();
    if (tid == 0) {
        float sx = 0.f;
#pragma unroll
        for (int q = 0; q < 16; ++q) sx += nsSh[q];
        atomicAdd(out, -sx * (LN2 / (float)N_TOT));   // out zeroed by pass1 block 0
    }
}

extern "C" void kernel_launch(void* const* d_in, const int* in_sizes, int n_in,
                              void* d_out, int out_size, void* d_ws, size_t ws_size,
                              hipStream_t stream) {
    const float* feats  = (const float*)d_in[0];
    const int*   labels = (const int*)d_in[1];
    float* out = (float*)d_out;

    char* ws = (char*)d_ws;
    float*  partNeg = (float*)(ws + (2u << 20));                    // 1 MB (4096*64 f32)
    float*  posBuf  = (float*)(ws + (3u << 20));                    // 8 MB

    k_pass1<<<NBLK, 256, 0, stream>>>(feats, labels, partNeg, posBuf, out);
    k_passB<<<N_ANCH, 256, 0, stream>>>(posBuf, labels, partNeg, out);
}

// Round 18
// 30.198 us; speedup vs baseline: 1.0639x; 1.0639x over previous
//
#include <hip/hip_runtime.h>
#include <hip/hip_bf16.h>

#define D_DIM   256
#define N_TOT   4096
#define N_ANCH  256
#define NGRP    32                    // anchor groups of 8 (128 rows)
#define NOFF    496                   // strict upper-triangle tiles (g<s)
#define NBLK    512                   // 496 off-diag + 16 dual-diagonal blocks
#define NPART   64                    // partAll slots per row
#define K1  20.60992915555662f        // (1/0.07) * log2(e)
#define LN2 0.6931471805599453f
#define MAXNP    48                   // max anchors per label (19 labels, mean 13.5)

typedef __attribute__((ext_vector_type(8))) short bf16x8;
typedef __attribute__((ext_vector_type(4))) float f32x4;

#define MFMA(a, b, c) __builtin_amdgcn_mfma_f32_16x16x32_bf16((a), (b), (c), 0, 0, 0)

__device__ __forceinline__ bf16x8 cvt8(const float4 a, const float4 b) {
    union { uint32_t w[4]; bf16x8 v; } u;
    asm("v_cvt_pk_bf16_f32 %0, %1, %2" : "=v"(u.w[0]) : "v"(a.x), "v"(a.y));
    asm("v_cvt_pk_bf16_f32 %0, %1, %2" : "=v"(u.w[1]) : "v"(a.z), "v"(a.w));
    asm("v_cvt_pk_bf16_f32 %0, %1, %2" : "=v"(u.w[2]) : "v"(b.x), "v"(b.y));
    asm("v_cvt_pk_bf16_f32 %0, %1, %2" : "=v"(u.w[3]) : "v"(b.z), "v"(b.w));
    return u.v;
}

// ---------- kernel 1: symmetric 128x128-tile fused GEMM (r13-validated, UNCHANGED) ----------
// 512 blocks: 0..495 strict-upper tiles (XCD-swizzled), 496..511 two diagonal tiles each.
// 256 threads = 4 waves (2x2); each wave 64x64 out. K=256 in two BK=128 chunks through
// one 64 KB swizzled LDS buffer. A chunk-1 is register-prefetched during compute(0);
// B chunk-1 stays load-after-barrier (A+B prefetch spills — r14 regression).
__global__ void __launch_bounds__(256, 2) k_pass1(const float* __restrict__ feats,
                                                  const int* __restrict__ labels,
                                                  float* __restrict__ partAll,
                                                  float* __restrict__ posBuf,
                                                  float* __restrict__ out) {
    __shared__ __align__(16) char lds[65536];   // A: [0,32K), B: [32K,64K)
    __shared__ int labS[N_ANCH];
    __shared__ int cntS[32];
    __shared__ int metaRank[16], metaToff[16];

    if (blockIdx.x == 0 && threadIdx.x == 0) out[0] = 0.f;   // passB accumulates later

    const int tid = threadIdx.x;
    const int lane = tid & 63, wid = tid >> 6;
    const int lrow = lane & 15, khalf = lane >> 4;
    const int wr = wid >> 1, wc = wid & 1;      // wave sub-tile (wr*64, wc*64)

    // label table + histogram (persists across tiles)
    labS[tid] = labels[tid];
    if (tid < 32) cntS[tid] = 0;
    __syncthreads();
    atomicAdd(&cntS[labS[tid]], 1);
    // (first in-tile __syncthreads covers the histogram)

    // staging decode: linear bf16 LDS byte L -> fp32 source offset + swizzled LDS byte
    uint32_t LgF[8], Lw[8];
#pragma unroll
    for (int o = 0; o < 8; ++o) {
        uint32_t L = (uint32_t)(tid * 16 + o * 4096);
        LgF[o] = (L >> 8) * 1024 + ((L & 255) << 1);       // row*1024B + colelem*4B
        Lw[o]  = L ^ (((L >> 8) & 7u) << 4);               // swizzled LDS byte
    }
    const uint32_t swz = (uint32_t)((lrow & 7) << 4);

    auto gemm_tile = [&](int g, int s) {
        const bool diag = (g == s);
        const char* aSrcF = (const char*)(feats + (size_t)g * 128 * D_DIM);
        const char* bSrcF = (const char*)(feats + (size_t)s * 128 * D_DIM);
        const uint32_t bBase = diag ? 0u : 32768u;   // diagonal: B-frags read A region

        f32x4 acc[4][4];
#pragma unroll
    for (int m = 0; m < 4; ++m)
#pragma unroll
        for (int n = 0; n < 4; ++n)
            acc[m][n] = (f32x4){0.f, 0.f, 0.f, 0.f};

        auto compute = [&]() {
#pragma unroll
            for (int ks = 0; ks < 4; ++ks) {
                bf16x8 af[4], bfr[4];
#pragma unroll
                for (int m = 0; m < 4; ++m) {
                    uint32_t row = (uint32_t)(wr * 64 + m * 16 + lrow);
                    af[m] = *(const bf16x8*)(lds + ((row * 256 + ks * 64 + khalf * 16) ^ swz));
                }
#pragma unroll
                for (int n = 0; n < 4; ++n) {
                    uint32_t row = (uint32_t)(wc * 64 + n * 16 + lrow);
                    bfr[n] = *(const bf16x8*)(lds + bBase + ((row * 256 + ks * 64 + khalf * 16) ^ swz));
                }
#pragma unroll
                for (int m = 0; m < 4; ++m)
#pragma unroll
                    for (int n = 0; n < 4; ++n)
                        acc[m][n] = MFMA(af[m], bfr[n], acc[m][n]);
            }
        };

        // ---- stage chunk 0 (A, and B if off-diag) ----
        {
            float4 fa[8][2], fb[8][2];
#pragma unroll
            for (int o = 0; o < 8; ++o) {
                const char* pa = aSrcF + LgF[o];
                fa[o][0] = *(const float4*)pa;  fa[o][1] = *(const float4*)(pa + 16);
            }
            if (!diag) {
#pragma unroll
                for (int o = 0; o < 8; ++o) {
                    const char* pb = bSrcF + LgF[o];
                    fb[o][0] = *(const float4*)pb;  fb[o][1] = *(const float4*)(pb + 16);
                }
            }
#pragma unroll
            for (int o = 0; o < 8; ++o)
                *(bf16x8*)(lds + Lw[o]) = cvt8(fa[o][0], fa[o][1]);
            if (!diag) {
#pragma unroll
                for (int o = 0; o < 8; ++o)
                    *(bf16x8*)(lds + 32768 + Lw[o]) = cvt8(fb[o][0], fb[o][1]);
            }
        }
        __syncthreads();        // chunk 0 ready (also covers histogram / prev tile)

        // ---- prefetch A chunk 1 into registers (latency hides under meta + compute 0) ----
        float4 pfa[8][2];
#pragma unroll
        for (int o = 0; o < 8; ++o) {
            const char* pa = aSrcF + LgF[o] + 512;
            pfa[o][0] = *(const float4*)pa;  pfa[o][1] = *(const float4*)(pa + 16);
        }

        // per-tile metadata: 16 anchors x 16 workers
        {
            int aIdx = tid >> 4, q = tid & 15;
            int aAnchor = (aIdx < 8) ? (g * 8 + aIdx) : (s * 8 + aIdx - 8);
            int la = labS[aAnchor];
            int rk = 0, tf = 0;
            for (int b = q; b < aAnchor; b += 16) {
                int lb = labS[b];
                rk += (lb == la);
                tf += cntS[lb];
            }
#pragma unroll
            for (int msk = 1; msk < 16; msk <<= 1) {
                rk += __shfl_xor(rk, msk, 64);
                tf += __shfl_xor(tf, msk, 64);
            }
            if (q == 0) { metaRank[aIdx] = rk; metaToff[aIdx] = tf; }
        }

        compute();              // chunk 0
        __syncthreads();        // reads of chunk 0 done

        // ---- stage chunk 1: write prefetched A; load+write B ----
#pragma unroll
        for (int o = 0; o < 8; ++o)
            *(bf16x8*)(lds + Lw[o]) = cvt8(pfa[o][0], pfa[o][1]);
        if (!diag) {
            float4 fb[8][2];
#pragma unroll
            for (int o = 0; o < 8; ++o) {
                const char* pb = bSrcF + LgF[o] + 512;
                fb[o][0] = *(const float4*)pb;  fb[o][1] = *(const float4*)(pb + 16);
            }
#pragma unroll
            for (int o = 0; o < 8; ++o)
                *(bf16x8*)(lds + 32768 + Lw[o]) = cvt8(fb[o][0], fb[o][1]);
        }
        __syncthreads();        // chunk 1 ready (meta visible)
        compute();
        __syncthreads();        // LDS free -> transpose scratch

        // ---- epilogue ----
        const int raBase = g * 8 + wr * 4, caBase = s * 8 + wc * 4;
        int labR[4], offR[4], rankR[4], labC[4], rankC[4], offC[4];
#pragma unroll
        for (int m = 0; m < 4; ++m) {
            labR[m]  = labS[raBase + m];
            offR[m]  = metaToff[wr * 4 + m];
            rankR[m] = metaRank[wr * 4 + m];
        }
#pragma unroll
        for (int n = 0; n < 4; ++n) {
            labC[n]  = labS[caBase + n];
            rankC[n] = metaRank[8 + wc * 4 + n];
            offC[n]  = metaToff[8 + wc * 4 + n];
        }

        float aAll[4][4];
        float colP[4];
#pragma unroll
        for (int m = 0; m < 4; ++m)
#pragma unroll
            for (int i = 0; i < 4; ++i) aAll[m][i] = 0.f;
#pragma unroll
        for (int n = 0; n < 4; ++n) colP[n] = 0.f;

        float* scr = (float*)lds + wid * 256;   // 1 KB per-wave transpose scratch

#pragma unroll
        for (int m = 0; m < 4; ++m) {
#pragma unroll
            for (int n = 0; n < 4; ++n) {
                f32x4 c = acc[m][n];
                float e[4];
#pragma unroll
                for (int i = 0; i < 4; ++i) {
                    e[i] = exp2f(__builtin_fmaf(c[i], K1, -K1));
                    aAll[m][i] += e[i];
                }
                if (!diag)
                    colP[n] += e[0] + e[1] + e[2] + e[3];
                if (labR[m] == labC[n]) {    // wave-uniform positive tile
                    *(f32x4*)(posBuf + (size_t)(offR[m] + rankC[n]) * 256 + lane * 4) = c;
                    if (!diag) {
#pragma unroll
                        for (int i = 0; i < 4; ++i)
                            scr[(khalf * 4 + i) * 16 + lrow] = c[i];
                        __builtin_amdgcn_s_waitcnt(0);          // wave-local LDS RAW
                        f32x4 tr = *(f32x4*)(scr + lrow * 16 + khalf * 4);
                        *(f32x4*)(posBuf + (size_t)(offC[n] + rankR[m]) * 256 + lane * 4) = tr;
                    }
                }
            }
        }

#pragma unroll
        for (int msk = 1; msk < 16; msk <<= 1)
#pragma unroll
            for (int m = 0; m < 4; ++m)
#pragma unroll
                for (int i = 0; i < 4; ++i)
                    aAll[m][i] += __shfl_xor(aAll[m][i], msk, 64);

        if (lrow == 0) {
#pragma unroll
            for (int m = 0; m < 4; ++m)
#pragma unroll
                for (int i = 0; i < 4; ++i) {
                    int row = g * 128 + wr * 64 + m * 16 + khalf * 4 + i;
                    partAll[row * NPART + s * 2 + wc] = aAll[m][i];
                }
        }

        if (!diag) {
#pragma unroll
            for (int msk = 16; msk < 64; msk <<= 1)
#pragma unroll
                for (int n = 0; n < 4; ++n)
                    colP[n] += __shfl_xor(colP[n], msk, 64);
            if (lane < 16) {
#pragma unroll
                for (int n = 0; n < 4; ++n) {
                    int row = s * 128 + wc * 64 + n * 16 + lane;
                    partAll[row * NPART + g * 2 + wr] = colP[n];
                }
            }
        }
        __syncthreads();        // scr reads done before any next-tile staging
    };

    if (blockIdx.x < NOFF) {
        // strict upper triangle (g<s), XCD-swizzled (496 = 8*62)
        int swzId = (blockIdx.x & 7) * 62 + (blockIdx.x >> 3);
        int rem = swzId, g = 0;
        while (rem >= NGRP - 1 - g) { rem -= NGRP - 1 - g; ++g; }
        gemm_tile(g, g + 1 + rem);
    } else {
        int j = blockIdx.x - NOFF;     // 0..15 -> two diagonal tiles each
        gemm_tile(2 * j, 2 * j);
        gemm_tile(2 * j + 1, 2 * j + 1);
    }
}

// ---------- kernel 2: positive pass + atomic final (parallelized reductions) ----------
__global__ void __launch_bounds__(256) k_passB(const float* __restrict__ posBuf,
                                               const int* __restrict__ labels,
                                               const float* __restrict__ partAll,
                                               float* __restrict__ out) {
    int rt  = blockIdx.x;
    int tid = threadIdx.x;
    int l = tid >> 2, i = tid & 3;
    int r   = (l >> 4) * 4 + i;        // row within tile (fixed per thread)
    int col = l & 15;
    int row16 = tid >> 4;              // reduction role: row
    int q16   = tid & 15;              //   and 16-way slice (contiguous lanes in-wave)

    __shared__ float tile[MAXNP * 256];
    __shared__ float shA[16][17];
    __shared__ float shB[16][17];
    __shared__ float nsSh[16], PSh[16];
    __shared__ int labS[N_ANCH];
    __shared__ int cntS[32];
    __shared__ int wRk[4], wTf[4];
    __shared__ int mNp, mOff, mRank;

    // in-block metadata for anchor rt
    labS[tid] = labels[tid];
    if (tid < 32) cntS[tid] = 0;
    __syncthreads();
    atomicAdd(&cntS[labS[tid]], 1);
    __syncthreads();
    {
        int la = labS[rt];
        int rk = 0, tf = 0;
        if (tid < rt) { int lb = labS[tid]; rk = (lb == la) ? 1 : 0; tf = cntS[lb]; }
#pragma unroll
        for (int msk = 1; msk < 64; msk <<= 1) {
            rk += __shfl_xor(rk, msk, 64);
            tf += __shfl_xor(tf, msk, 64);
        }
        if ((tid & 63) == 0) { wRk[tid >> 6] = rk; wTf[tid >> 6] = tf; }
        __syncthreads();
        if (tid == 0) {
            mNp   = cntS[la];
            mRank = wRk[0] + wRk[1] + wRk[2] + wRk[3];
            mOff  = wTf[0] + wTf[1] + wTf[2] + wTf[3];
        }
        __syncthreads();
    }
    int np = mNp, off = mOff, selfRank = mRank;

    // loop 1: exp sums + positive logit sums; cache exp2 values in LDS
    float sE = 0.f, sP = 0.f;
    const float* src = posBuf + (size_t)off * 256 + tid;
    for (int j = 0; j < np; ++j) {
        float c = src[j * 256];
        float l2 = __builtin_fmaf(c, K1, -K1);
        float e = exp2f(l2);
        tile[j * 256 + tid] = e;           // cache e (loop 2 needs only e + ns)
        sE += e;
        bool diag = (j == selfRank) & (col == r);
        sP += diag ? 0.f : l2;
    }
    shA[r][col] = sE;
    shB[r][col] = sP;
    __syncthreads();

    // parallel reduce 1: thread (row16,q16) — sall (64 slots as 16 float4), e, p
    {
        const float* pa = partAll + (size_t)(rt * 16 + row16) * NPART + q16 * 4;
        float4 v = *(const float4*)pa;
        float sall = v.x + v.y + v.z + v.w;
        float e = shA[row16][q16];
        float p = shB[row16][q16];
#pragma unroll
        for (int msk = 1; msk < 16; msk <<= 1) {
            sall += __shfl_xor(sall, msk, 64);
            e    += __shfl_xor(e,    msk, 64);
            p    += __shfl_xor(p,    msk, 64);
        }
        if (q16 == 0) { nsSh[row16] = sall - e; PSh[row16] = p; }
    }
    __syncthreads();

    // loop 2: L = sum log2(e + ns)  (e from LDS — no exp2 on this path)
    float nsv = nsSh[r];
    float sL = 0.f;
    for (int j = 0; j < np; ++j) {
        float e = tile[j * 256 + tid];
        float lg = __log2f(e + nsv);
        bool diag = (j == selfRank) & (col == r);
        sL += diag ? 0.f : lg;
    }
    __syncthreads();
    shA[r][col] = sL;
    __syncthreads();

    // parallel reduce 2: per-row L, then per-row contribution
    {
        float L = shA[row16][q16];
#pragma unroll
        for (int msk = 1; msk < 16; msk <<= 1)
            L += __shfl_xor(L, msk, 64);
        if (q16 == 0)
            shB[0][row16] = (PSh[row16] - L) / (float)(16 * np - 1);
    }
    __syncthreads();
    if (tid == 0) {
        float sx = 0.f;
#pragma unroll
        for (int q = 0; q < 16; ++q) sx += shB[0][q];
        atomicAdd(out, -sx * (LN2 / (float)N_TOT));   // out zeroed by pass1 block 0
    }
}

extern "C" void kernel_launch(void* const* d_in, const int* in_sizes, int n_in,
                              void* d_out, int out_size, void* d_ws, size_t ws_size,
                              hipStream_t stream) {
    const float* feats  = (const float*)d_in[0];
    const int*   labels = (const int*)d_in[1];
    float* out = (float*)d_out;

    char* ws = (char*)d_ws;
    float*  partAll = (float*)(ws + (2u << 20));                    // 1 MB (4096*64 f32)
    float*  posBuf  = (float*)(ws + (3u << 20));                    // 8 MB

    k_pass1<<<NBLK, 256, 0, stream>>>(feats, labels, partAll, posBuf, out);
    k_passB<<<N_ANCH, 256, 0, stream>>>(posBuf, labels, partAll, out);
}